// Round 2
// baseline (461.333 us; speedup 1.0000x reference)
//
#include <hip/hip_runtime.h>

// Problem: Sampler — pooled = mean over stride-2 grid of b, then 2 tiny FCs.
// b: [8,128,256,256] f32. Output: [8,128,1,1] f32 (1024 elems).
//
// R2 change: pool_kernel previously fetched ONLY even rows (1 KB used per
// 2 KB span -> every address has bit 10 == 0 -> channel/bank-hash starvation
// and ~50% DRAM page efficiency; measured ~1.4 TB/s vs 6.55 TB/s that the
// harness's own fills reach). Now each block streams its plane CONTIGUOUSLY:
// even-row float4 loads feed the sum (accumulation order bit-identical to the
// passing kernel), and one sparse dword load per odd row touches every cache
// line so the fetch is a pure 256-KB/block stream. Odd-row values are kept
// live with an empty asm (else DCE restores the stride-2 pattern).
// pooled intermediate still lives in d_out; d_ws untouched.

#define B_DIM 8
#define C_DIM 128
#define H_DIM 256
#define W_DIM 256
#define HWSZ  (H_DIM * W_DIM)      // 65536
#define NPLANE (B_DIM * C_DIM)     // 1024

__global__ __launch_bounds__(256) void pool_kernel(const float* __restrict__ b,
                                                   float* __restrict__ pooled) {
    const int plane = blockIdx.x;                 // 0..1023
    const float* base = b + (size_t)plane * HWSZ;
    const int tid  = threadIdx.x;
    const int col4 = tid & 63;                    // float4 index within row (0..63)
    const int rq   = tid >> 6;                    // wave id 0..3

    float acc = 0.f;
    #pragma unroll 8
    for (int i = 0; i < 32; ++i) {
        const int er  = rq + 4 * i;               // even-row index 0..127
        const int row = er << 1;                  // actual row (even)
        // compute load: full even row, 64 lanes x 16 B (accumulation order
        // identical to the previous passing kernel)
        float4 v = ((const float4*)(base + (size_t)row * W_DIM))[col4];
        acc += v.x + v.z;                         // even columns only

        // touch load: odd row row+1, one dword per 16 B across the wave
        // (64 lanes cover the full 1-KB row -> every 64-B line fetched).
        float t = base[(size_t)(row + 1) * W_DIM + (col4 << 2)];
        asm volatile("" : : "v"(t));              // keep the load alive
    }

    // wave (64-lane) tree reduce — unchanged
    #pragma unroll
    for (int off = 32; off > 0; off >>= 1)
        acc += __shfl_down(acc, off, 64);

    __shared__ float ws[4];
    if ((tid & 63) == 0) ws[rq] = acc;
    __syncthreads();
    if (tid == 0)
        pooled[plane] = (ws[0] + ws[1] + ws[2] + ws[3]) * (1.0f / 65536.0f);
}

// Kernel 2: hidden = relu(pooled @ fc1^T) ; out = hidden @ fc2^T.
// One block per batch (8 blocks x 256 threads). Block bb reads ONLY its own
// pooled row out[bb*128 .. +127] (written by kernel 1), stages it in LDS
// behind a __syncthreads, then overwrites that same range. LDS rows padded
// (+1) against same-bank serialization.
__global__ __launch_bounds__(256) void fc_kernel(const float* __restrict__ fc1_w,  // [32,128]
                                                 const float* __restrict__ fc2_w,  // [128,32]
                                                 float* out) {                     // [8,128], holds pooled on entry
    __shared__ float sp[C_DIM];
    __shared__ float s_fc1[32 * 129];
    __shared__ float s_fc2[128 * 33];
    __shared__ float sh[32];

    const int bb  = blockIdx.x;                   // batch 0..7
    const int tid = threadIdx.x;

    if (tid < 32) {
        float4 v = ((const float4*)(out + bb * C_DIM))[tid];
        float* d = sp + tid * 4;
        d[0] = v.x; d[1] = v.y; d[2] = v.z; d[3] = v.w;
    }
    for (int i4 = tid; i4 < 1024; i4 += 256) {
        float4 v = ((const float4*)fc1_w)[i4];
        const int j = i4 >> 5, c4 = (i4 & 31) * 4;
        float* d = s_fc1 + j * 129 + c4;
        d[0] = v.x; d[1] = v.y; d[2] = v.z; d[3] = v.w;
    }
    for (int i4 = tid; i4 < 1024; i4 += 256) {
        float4 v = ((const float4*)fc2_w)[i4];
        const int o = i4 >> 3, j4 = (i4 & 7) * 4;
        float* d = s_fc2 + o * 33 + j4;
        d[0] = v.x; d[1] = v.y; d[2] = v.z; d[3] = v.w;
    }
    __syncthreads();

    if (tid < 32) {
        const float* w = s_fc1 + tid * 129;
        float h = 0.f;
        #pragma unroll
        for (int c = 0; c < C_DIM; ++c) h += sp[c] * w[c];
        sh[tid] = h > 0.f ? h : 0.f;
    }
    __syncthreads();

    if (tid < 128) {
        const float* w = s_fc2 + tid * 33;
        float a = 0.f;
        #pragma unroll
        for (int j = 0; j < 32; ++j) a += sh[j] * w[j];
        out[bb * C_DIM + tid] = a;
    }
}

extern "C" void kernel_launch(void* const* d_in, const int* in_sizes, int n_in,
                              void* d_out, int out_size, void* d_ws, size_t ws_size,
                              hipStream_t stream) {
    const float* b     = (const float*)d_in[1];
    const float* fc1_w = (const float*)d_in[4];
    const float* fc2_w = (const float*)d_in[5];
    float* out = (float*)d_out;
    (void)d_ws; (void)ws_size;                    // workspace intentionally untouched

    pool_kernel<<<NPLANE, 256, 0, stream>>>(b, out);   // d_out holds pooled
    fc_kernel<<<B_DIM, 256, 0, stream>>>(fc1_w, fc2_w, out);
}